// Round 9
// baseline (1470.378 us; speedup 1.0000x reference)
//
#include <hip/hip_runtime.h>
#include <hip/hip_bf16.h>
#include <math.h>

// ---------------------------------------------------------------------------
// InferenceEngine: B=8 S=1024 H=1024 M=4 STEPS=5, all fp32 I/O.
// Round 9: occupancy experiment — 128x128 tile (MF=4,NF=2,BK=64) => 64 KB LDS
// => 2 blocks/CU, launch_bounds(512,4) caps VGPR at 128. r4 2-barrier
// schedule unchanged (frozen). Hypothesis: co-resident block fills the
// barrier-drain stall that capped all 1-block/CU variants at ~41% MfmaUtil.
// ---------------------------------------------------------------------------

typedef unsigned short bf16_t;
typedef __attribute__((ext_vector_type(8))) short s8v;   // 8 x bf16 (4 VGPR)
typedef __attribute__((ext_vector_type(4))) float f4v;   // MFMA acc

typedef const __attribute__((address_space(1))) void* gas_ptr;
typedef __attribute__((address_space(3))) void* las_ptr;

#define DEVFN static __device__ __forceinline__

DEVFN bf16_t f2b(float f) {
    union { float f; unsigned u; } v; v.f = f;
    unsigned r = v.u + 0x7FFFu + ((v.u >> 16) & 1u);   // RNE
    return (bf16_t)(r >> 16);
}
DEVFN float b2f(bf16_t b) {
    union { unsigned u; float f; } v; v.u = ((unsigned)b) << 16; return v.f;
}
DEVFN float geluf(float x) { return 0.5f * x * (1.0f + erff(x * 0.70710678118654752f)); }
DEVFN float sigmf(float x) { return 1.0f / (1.0f + expf(-x)); }

// ------------------------- output layout (floats) ---------------------------
static const long OUT_RESULT = 0;           // 8*1024*1024
static const long OUT_MODE   = 8388608;     // 8*2
static const long OUT_DEPTH  = 8388624;     // 8*5
static const long OUT_EXPL   = 8388664;     // 8*1024*1024
static const long OUT_IMPL   = 16777272;    // 8*1024*4096

static const long SLAB = 8388608;           // elements per state slab

// ---------------------------------------------------------------------------
// GEMM (r4 2-barrier schedule, frozen). C = A * Bt^T.
// 512 thr = 8 waves (2M x 4N). BM = MF*32, BN = NF*64, BK = 64.
// blockIdx.z selects pointer set {A,Bt,bias,out} (dual-GEMM launches).
//   ph1: READ A-hi + B-hi (buf c)   ; MFMA q(0,0)
//   ph2: MFMA q(1,0)                ; lgkmcnt(0) ; bar
//   ph3: stage tile t+2 -> buf c    ; MFMA q(1,1) ; vmcnt(LPT) ; bar
//   ph4: READ B-lo (c^1) ; MFMA q(0,1) ; READ A-lo (c^1)
// EPI: 1 = gelu(+bias1d) ; 2 = gelu(+bias2d[batch]) ; 3 = +bias1d  (bf16 out)
// ---------------------------------------------------------------------------
#define READ_A(h, c_) { _Pragma("unroll") \
    for (int mf = 0; mf < MF / 2; ++mf) { _Pragma("unroll") \
      for (int ks = 0; ks < 2; ++ks) { \
        aA[h][mf][ks] = *(const s8v*)(lds + (c_) * BUFB + \
            (arow_base + ((h) * (MF / 2) + mf) * 16) * 128 + \
            ((((ks << 2) + lhi) ^ l7) << 4)); } } }

#define READ_B(h, c_) { _Pragma("unroll") \
    for (int nf = 0; nf < NF / 2; ++nf) { _Pragma("unroll") \
      for (int ks = 0; ks < 2; ++ks) { \
        bB[h][nf][ks] = *(const s8v*)(lds + (c_) * BUFB + ABYTES + \
            (brow_base + ((h) * (NF / 2) + nf) * 16) * 128 + \
            ((((ks << 2) + lhi) ^ l7) << 4)); } } }

#define MFMAQ(mh, nh) { __builtin_amdgcn_s_setprio(1); _Pragma("unroll") \
    for (int mf = 0; mf < MF / 2; ++mf) { _Pragma("unroll") \
      for (int nf = 0; nf < NF / 2; ++nf) { _Pragma("unroll") \
        for (int ks = 0; ks < 2; ++ks) { \
          acc[(mh) * (MF / 2) + mf][(nh) * (NF / 2) + nf] = \
            __builtin_amdgcn_mfma_f32_16x16x32_bf16(aA[mh][mf][ks], bB[nh][nf][ks], \
                acc[(mh) * (MF / 2) + mf][(nh) * (NF / 2) + nf], 0, 0, 0); } } } \
    __builtin_amdgcn_s_setprio(0); }

#define WAIT_VM_LPT() { if (LPT == 8)      asm volatile("s_waitcnt vmcnt(8)" ::: "memory"); \
                        else if (LPT == 6) asm volatile("s_waitcnt vmcnt(6)" ::: "memory"); \
                        else               asm volatile("s_waitcnt vmcnt(4)" ::: "memory"); }

template <int MF, int NF, int EPI>
__global__ __launch_bounds__(512, 4) void gemm8p(
    const bf16_t* __restrict__ A0, const bf16_t* __restrict__ Bt0,
    const float* __restrict__ bias0, bf16_t* __restrict__ out0,
    const bf16_t* __restrict__ A1, const bf16_t* __restrict__ Bt1,
    const float* __restrict__ bias1, bf16_t* __restrict__ out1,
    int N, int K)
{
    constexpr int BM = MF * 32;
    constexpr int BN = NF * 64;
    constexpr int LA = BM / 64;          // A global_load_lds per thread per tile
    constexpr int LB = BN / 64;
    constexpr int LPT = LA + LB;
    constexpr int ABYTES = BM * 128;     // BM rows x 64 k x 2B
    constexpr int BUFB = (BM + BN) * 128;

    __shared__ __align__(16) char lds[2 * BUFB];

    // pointer-set select (wave-uniform SGPR select)
    const bf16_t* A    = blockIdx.z ? A1 : A0;
    const bf16_t* Bt   = blockIdx.z ? Bt1 : Bt0;
    const float*  bias = blockIdx.z ? bias1 : bias0;
    bf16_t*       outB = blockIdx.z ? out1 : out0;

    const int tid  = threadIdx.x;
    const int lane = tid & 63;
    const int wave = tid >> 6;
    const int wm = wave >> 2, wn = wave & 3;
    const int l15 = lane & 15, lhi = lane >> 4, l7 = lane & 7;

    // T1: bijective XCD-chunked swizzle (per z-slice)
    const int gx = gridDim.x;
    const int nwg = gx * gridDim.y;
    const int orig = blockIdx.y * gx + blockIdx.x;
    const int qq = nwg >> 3, rr8 = nwg & 7;
    const int xcd = orig & 7, lid = orig >> 3;
    const int nid = (xcd < rr8 ? xcd * (qq + 1) : rr8 * (qq + 1) + (xcd - rr8) * qq) + lid;
    const int m0 = (nid / gx) * BM;
    const int n0 = (nid % gx) * BN;

    const int NT = K >> 6;

    const int arow_base = wm * (BM / 2) + l15;
    const int brow_base = wn * (NF * 16) + l15;

    f4v acc[MF][NF];
#pragma unroll
    for (int i = 0; i < MF; ++i)
#pragma unroll
        for (int j = 0; j < NF; ++j)
#pragma unroll
            for (int q2 = 0; q2 < 4; ++q2) acc[i][j][q2] = 0.0f;

    s8v aA[2][MF / 2][2];
    s8v bB[2][NF / 2][2];

    auto stage = [&](int ts, int tb) {
        const int kt = ts << 6;
#pragma unroll
        for (int i = 0; i < LA; ++i) {
            const int li = i * 512 + tid;
            const int r = li >> 3, s = li & 7;
            const bf16_t* src = A + (long)(m0 + r) * K + kt + ((s ^ (r & 7)) << 3);
            __builtin_amdgcn_global_load_lds((gas_ptr)src, (las_ptr)(lds + tb * BUFB + li * 16), 16, 0, 0);
        }
#pragma unroll
        for (int i = 0; i < LB; ++i) {
            const int li = i * 512 + tid;
            const int r = li >> 3, s = li & 7;
            const bf16_t* src = Bt + (long)(n0 + r) * K + kt + ((s ^ (r & 7)) << 3);
            __builtin_amdgcn_global_load_lds((gas_ptr)src, (las_ptr)(lds + tb * BUFB + ABYTES + li * 16), 16, 0, 0);
        }
    };

    // prologue: tiles 0,1 in flight; wait tile 0; first q1 operands
    stage(0, 0);
    stage(1, 1);
    WAIT_VM_LPT();
    __builtin_amdgcn_sched_barrier(0);
    __builtin_amdgcn_s_barrier();
    READ_A(0, 0);
    READ_B(0, 0);

    for (int t = 0; t < NT; ++t) {
        const int c = t & 1;
        // ph1: hi-half reads issued a full quadrant before their first use
        READ_A(1, c);
        READ_B(1, c);
        MFMAQ(0, 0);
        // ph2
        MFMAQ(1, 0);
        asm volatile("s_waitcnt lgkmcnt(0)" ::: "memory");
        __builtin_amdgcn_sched_barrier(0);
        __builtin_amdgcn_s_barrier();                 // B1: all buf[c] reads retired
        // ph3
        int ts = t + 2; if (ts >= NT) ts -= NT;       // wrap: harmless warm re-stage
        stage(ts, c);
        MFMAQ(1, 1);
        WAIT_VM_LPT();                                // tile t+1 fully in buf[c^1]
        __builtin_amdgcn_sched_barrier(0);
        __builtin_amdgcn_s_barrier();                 // B2
        // ph4: B-lo read first (bB[0] dead since ph2), then MFMA frees aA[0]
        READ_B(0, c ^ 1);
        MFMAQ(0, 1);
        READ_A(0, c ^ 1);
    }

    // epilogue. C/D layout: col = lane&15, row = (lane>>4)*4 + q
    const int crr = lhi << 2;
#pragma unroll
    for (int mi = 0; mi < MF; ++mi) {
#pragma unroll
        for (int ni = 0; ni < NF; ++ni) {
            const int col = n0 + wn * (NF * 16) + ni * 16 + (lane & 15);
#pragma unroll
            for (int q2 = 0; q2 < 4; ++q2) {
                const int row = m0 + wm * (BM / 2) + mi * 16 + crr + q2;
                const float v = acc[mi][ni][q2];
                if (EPI == 1) {
                    outB[(long)row * N + col] = f2b(geluf(v + bias[col]));
                } else if (EPI == 2) {
                    outB[(long)row * N + col] = f2b(geluf(v + bias[(long)(row >> 10) * N + col]));
                } else {
                    outB[(long)row * N + col] = f2b(v + bias[col]);
                }
            }
        }
    }
}

// --------------------- transpose f32[K,N] -> bf16[N,K] ----------------------
__global__ __launch_bounds__(256) void transpose_k(
    const float* __restrict__ src, bf16_t* __restrict__ dst,
    int K, int N, long sbs, long dbs)
{
    __shared__ float tile[32][33];
    const float* s = src + (long)blockIdx.z * sbs;
    bf16_t* d = dst + (long)blockIdx.z * dbs;
    const int n0 = blockIdx.x * 32, k0 = blockIdx.y * 32;
    const int tx = threadIdx.x, ty = threadIdx.y;   // 32 x 8
#pragma unroll
    for (int i = 0; i < 4; ++i)
        tile[ty + i * 8][tx] = s[(long)(k0 + ty + i * 8) * N + n0 + tx];
    __syncthreads();
#pragma unroll
    for (int i = 0; i < 4; ++i)
        d[(long)(n0 + ty + i * 8) * K + k0 + tx] = f2b(tile[tx][ty + i * 8]);
}

// --------------------------- f32 -> bf16 convert ----------------------------
__global__ __launch_bounds__(256) void cvt_k(const float4* __restrict__ src,
                                             ushort4* __restrict__ dst, int n4)
{
    const int i = blockIdx.x * 256 + threadIdx.x;
    if (i < n4) {
        float4 v = src[i];
        ushort4 o; o.x = f2b(v.x); o.y = f2b(v.y); o.z = f2b(v.z); o.w = f2b(v.w);
        dst[i] = o;
    }
}

// ---------------------------------------------------------------------------
// colgemv8: out[t*ots + b*Wld + j] = act(bias[t*bts+j] + sum_k ctx[b][k]*W[t*wts+k*Wld+j])
// ---------------------------------------------------------------------------
__global__ __launch_bounds__(256) void colgemv8_k(
    const float* __restrict__ ctx, const float* __restrict__ Wbase, long wts,
    int Wld, const float* __restrict__ bias, long bts,
    float* __restrict__ out, long ots, int do_gelu)
{
    __shared__ float cs[8][1024];
    __shared__ float rr[16][16][8];
    const int j0 = blockIdx.x * 16;
    const int t = blockIdx.y;
    const int tid = threadIdx.x;
    for (int i = tid; i < 2048; i += 256)
        ((float4*)cs)[i] = ((const float4*)ctx)[i];
    __syncthreads();
    const int kp = tid >> 4, jj = tid & 15;
    const float* Wp = Wbase + (long)t * wts;
    float p[8] = {0, 0, 0, 0, 0, 0, 0, 0};
    for (int i = 0; i < 64; ++i) {
        const int k = kp * 64 + i;
        const float w = Wp[(long)k * Wld + j0 + jj];
#pragma unroll
        for (int b = 0; b < 8; ++b) p[b] = fmaf(cs[b][k], w, p[b]);
    }
#pragma unroll
    for (int b = 0; b < 8; ++b) rr[kp][jj][b] = p[b];
    __syncthreads();
    if (tid < 128) {
        const int jj2 = tid >> 3, b = tid & 7;
        float s = 0.f;
#pragma unroll
        for (int k2 = 0; k2 < 16; ++k2) s += rr[k2][jj2][b];
        s += bias[(long)t * bts + j0 + jj2];
        if (do_gelu) s = geluf(s);
        out[(long)t * ots + (long)b * Wld + j0 + jj2] = s;
    }
}

// -------------- selectors tail: [8,2] and [8,5] softmaxes -------------------
__global__ __launch_bounds__(256) void selB_k(
    const float* __restrict__ h1, const float* __restrict__ hd,
    const float* __restrict__ Wm2, const float* __restrict__ bm2,
    const float* __restrict__ Wd2, const float* __restrict__ bd2,
    float* __restrict__ outM, float* __restrict__ outD,
    float* __restrict__ wsM, float* __restrict__ wsD)
{
    const int b = blockIdx.x, tid = threadIdx.x;
    __shared__ float red[256];
    float lm[2], ld[5];
    for (int o = 0; o < 2; ++o) {
        float p = 0.f;
        for (int k = tid; k < 1024; k += 256) p += h1[b * 1024 + k] * Wm2[k * 2 + o];
        red[tid] = p; __syncthreads();
        for (int s = 128; s > 0; s >>= 1) { if (tid < s) red[tid] += red[tid + s]; __syncthreads(); }
        lm[o] = red[0] + bm2[o]; __syncthreads();
    }
    for (int o = 0; o < 5; ++o) {
        float p = 0.f;
        for (int k = tid; k < 512; k += 256) p += hd[b * 512 + k] * Wd2[k * 5 + o];
        red[tid] = p; __syncthreads();
        for (int s = 128; s > 0; s >>= 1) { if (tid < s) red[tid] += red[tid + s]; __syncthreads(); }
        ld[o] = red[0] + bd2[o]; __syncthreads();
    }
    if (tid == 0) {
        float mx = fmaxf(lm[0], lm[1]);
        float e0 = expf(lm[0] - mx), e1 = expf(lm[1] - mx);
        float inv = 1.f / (e0 + e1);
        outM[b * 2] = e0 * inv; outM[b * 2 + 1] = e1 * inv;
        wsM[b * 2] = e0 * inv;  wsM[b * 2 + 1] = e1 * inv;
        float md = ld[0];
        for (int o = 1; o < 5; ++o) md = fmaxf(md, ld[o]);
        float es[5]; float sum = 0.f;
        for (int o = 0; o < 5; ++o) { es[o] = expf(ld[o] - md); sum += es[o]; }
        for (int o = 0; o < 5; ++o) { outD[b * 5 + o] = es[o] / sum; wsD[b * 5 + o] = es[o] / sum; }
    }
}

// --------------------- LayerNorm over 1024 (bf16 in/out) --------------------
__global__ __launch_bounds__(256) void ln1024_k(
    const bf16_t* __restrict__ X, const float* __restrict__ g,
    const float* __restrict__ b, bf16_t* __restrict__ Yb)
{
    const int row = blockIdx.x, tid = threadIdx.x;
    const ushort4 xv = ((const ushort4*)(X + (long)row * 1024))[tid];
    const float x0 = b2f(xv.x), x1 = b2f(xv.y), x2 = b2f(xv.z), x3 = b2f(xv.w);
    float s = x0 + x1 + x2 + x3;
    float ss = x0 * x0 + x1 * x1 + x2 * x2 + x3 * x3;
#pragma unroll
    for (int o = 32; o > 0; o >>= 1) { s += __shfl_down(s, o); ss += __shfl_down(ss, o); }
    __shared__ float rs[4], rss[4];
    const int wv = tid >> 6, ln = tid & 63;
    if (ln == 0) { rs[wv] = s; rss[wv] = ss; }
    __syncthreads();
    const float S = rs[0] + rs[1] + rs[2] + rs[3];
    const float SS = rss[0] + rss[1] + rss[2] + rss[3];
    const float mean = S * (1.0f / 1024.0f);
    const float var = SS * (1.0f / 1024.0f) - mean * mean;
    const float rstd = rsqrtf(var + 1e-5f);
    const float4 gv = ((const float4*)g)[tid];
    const float4 bv = ((const float4*)b)[tid];
    ushort4 ob;
    ob.x = f2b((x0 - mean) * rstd * gv.x + bv.x);
    ob.y = f2b((x1 - mean) * rstd * gv.y + bv.y);
    ob.z = f2b((x2 - mean) * rstd * gv.z + bv.z);
    ob.w = f2b((x3 - mean) * rstd * gv.w + bv.w);
    ((ushort4*)(Yb + (long)row * 1024))[tid] = ob;
}

// ------------------- GRU gate; writes mem + gated state slab ----------------
template <bool FIRST>
__global__ __launch_bounds__(256) void gru_k(
    const bf16_t* __restrict__ gi, const bf16_t* __restrict__ gh,
    const float* __restrict__ bhh, const bf16_t* __restrict__ nsB,
    bf16_t* __restrict__ memB, bf16_t* __restrict__ stateOut)
{
    const long i4 = (long)blockIdx.x * 256 + threadIdx.x;
    const long row = i4 >> 8;
    const int h4 = (int)(i4 & 255) << 2;
    const bf16_t* gir = gi + row * 3072 + h4;
    const ushort4 vir = *(const ushort4*)(gir);
    const ushort4 viz = *(const ushort4*)(gir + 1024);
    const ushort4 vin = *(const ushort4*)(gir + 2048);
    float hr[4], hz[4], hn[4];
    if (FIRST) {
        const float4 a = *(const float4*)(bhh + h4);
        const float4 c = *(const float4*)(bhh + 1024 + h4);
        const float4 d = *(const float4*)(bhh + 2048 + h4);
        hr[0] = a.x; hr[1] = a.y; hr[2] = a.z; hr[3] = a.w;
        hz[0] = c.x; hz[1] = c.y; hz[2] = c.z; hz[3] = c.w;
        hn[0] = d.x; hn[1] = d.y; hn[2] = d.z; hn[3] = d.w;
    } else {
        const bf16_t* ghr = gh + row * 3072 + h4;
        const ushort4 g1 = *(const ushort4*)(ghr);
        const ushort4 g2 = *(const ushort4*)(ghr + 1024);
        const ushort4 g3 = *(const ushort4*)(ghr + 2048);
        hr[0] = b2f(g1.x); hr[1] = b2f(g1.y); hr[2] = b2f(g1.z); hr[3] = b2f(g1.w);
        hz[0] = b2f(g2.x); hz[1] = b2f(g2.y); hz[2] = b2f(g2.z); hz[3] = b2f(g2.w);
        hn[0] = b2f(g3.x); hn[1] = b2f(g3.y); hn[2] = b2f(g3.z); hn[3] = b2f(g3.w);
    }
    const ushort4 nsv = *(const ushort4*)(nsB + row * 1024 + h4);
    float mo[4] = {0.f, 0.f, 0.f, 0.f};
    if (!FIRST) {
        const ushort4 mv = *(const ushort4*)(memB + row * 1024 + h4);
        mo[0] = b2f(mv.x); mo[1] = b2f(mv.y); mo[2] = b2f(mv.z); mo[3] = b2f(mv.w);
    }
    const float ir[4] = {b2f(vir.x), b2f(vir.y), b2f(vir.z), b2f(vir.w)};
    const float iz[4] = {b2f(viz.x), b2f(viz.y), b2f(viz.z), b2f(viz.w)};
    const float in_[4] = {b2f(vin.x), b2f(vin.y), b2f(vin.z), b2f(vin.w)};
    const float ns[4] = {b2f(nsv.x), b2f(nsv.y), b2f(nsv.z), b2f(nsv.w)};
    ushort4 mnb, stb;
    float mn[4], gt[4];
#pragma unroll
    for (int i = 0; i < 4; ++i) {
        const float rg = sigmf(ir[i] + hr[i]);
        const float zg = sigmf(iz[i] + hz[i]);
        const float ng = tanhf(in_[i] + rg * hn[i]);
        mn[i] = (1.0f - zg) * ng + zg * mo[i];
        gt[i] = ns[i] + 0.1f * mn[i];
    }
    mnb.x = f2b(mn[0]); mnb.y = f2b(mn[1]); mnb.z = f2b(mn[2]); mnb.w = f2b(mn[3]);
    stb.x = f2b(gt[0]); stb.y = f2b(gt[1]); stb.z = f2b(gt[2]); stb.w = f2b(gt[3]);
    *(ushort4*)(memB + row * 1024 + h4) = mnb;
    *(ushort4*)(stateOut + row * 1024 + h4) = stb;
}

// --- implicit LN (4096) + implicit_det + expl-from-slabs + final combine ----
__global__ __launch_bounds__(1024) void ln4096_final_k(
    const bf16_t* __restrict__ Ypre, const float* __restrict__ g,
    const float* __restrict__ b, const bf16_t* __restrict__ stS,
    const float* __restrict__ depthw, float* __restrict__ implOut,
    float* __restrict__ explOut, float* __restrict__ result,
    const float* __restrict__ modew)
{
    const int row = blockIdx.x, tid = threadIdx.x;
    const ushort4 xv = ((const ushort4*)(Ypre + (long)row * 4096))[tid];
    const float x0 = b2f(xv.x), x1 = b2f(xv.y), x2 = b2f(xv.z), x3 = b2f(xv.w);
    float s = x0 + x1 + x2 + x3;
    float ss = x0 * x0 + x1 * x1 + x2 * x2 + x3 * x3;
#pragma unroll
    for (int o = 32; o > 0; o >>= 1) { s += __shfl_down(s, o); ss += __shfl_down(ss, o); }
    __shared__ float rs[16], rss[16];
    __shared__ float ylds[4096];
    const int wv = tid >> 6, ln = tid & 63;
    if (ln == 0) { rs[wv] = s; rss[wv] = ss; }
    __syncthreads();
    if (tid < 64) {
        float a = (ln < 16) ? rs[ln] : 0.f;
        float c2 = (ln < 16) ? rss[ln] : 0.f;
#pragma unroll
        for (int o = 8; o > 0; o >>= 1) { a += __shfl_down(a, o); c2 += __shfl_down(c2, o); }
        if (ln == 0) { rs[0] = a; rss[0] = c2; }
    }
    __syncthreads();
    const float mean = rs[0] * (1.f / 4096.f);
    const float var = rss[0] * (1.f / 4096.f) - mean * mean;
    const float rstd = rsqrtf(var + 1e-5f);
    const float4 gv = ((const float4*)g)[tid];
    const float4 bv = ((const float4*)b)[tid];
    float4 y;
    y.x = (x0 - mean) * rstd * gv.x + bv.x;
    y.y = (x1 - mean) * rstd * gv.y + bv.y;
    y.z = (x2 - mean) * rstd * gv.z + bv.z;
    y.w = (x3 - mean) * rstd * gv.w + bv.w;
    ((float4*)(implOut + (long)row * 4096))[tid] = y;
    ((float4*)ylds)[tid] = y;
    __syncthreads();
    const int bidx = row >> 10;
    const long off = (long)row * 1024 + tid;
    float ex = 0.f;
#pragma unroll
    for (int tt = 0; tt < 5; ++tt)
        ex += depthw[bidx * 5 + tt] * b2f(stS[(long)tt * SLAB + off]);
    explOut[off] = ex;
    const float det4 = 0.25f * (ylds[tid] + ylds[tid + 1024] + ylds[tid + 2048] + ylds[tid + 3072]);
    result[off] = modew[bidx * 2] * det4 + modew[bidx * 2 + 1] * ex;
}

// ---------------------------------------------------------------------------
extern "C" void kernel_launch(void* const* d_in, const int* in_sizes, int n_in,
                              void* d_out, int out_size, void* d_ws, size_t ws_size,
                              hipStream_t stream)
{
    const float* det    = (const float*)d_in[0];
    const float* super_ = (const float*)d_in[1];
    const float* ctx    = (const float*)d_in[2];
    const float* Wm1 = (const float*)d_in[3];
    const float* bm1 = (const float*)d_in[4];
    const float* Wm2 = (const float*)d_in[5];
    const float* bm2 = (const float*)d_in[6];
    const float* Wd1 = (const float*)d_in[7];
    const float* bd1 = (const float*)d_in[8];
    const float* Wd2 = (const float*)d_in[9];
    const float* bd2 = (const float*)d_in[10];
    const float* We1 = (const float*)d_in[11];
    const float* be1 = (const float*)d_in[12];
    const float* We2 = (const float*)d_in[13];
    const float* be2 = (const float*)d_in[14];
    const float* ln_g = (const float*)d_in[15];
    const float* ln_b = (const float*)d_in[16];
    const float* W_ih = (const float*)d_in[17];
    const float* W_hh = (const float*)d_in[18];
    const float* b_ih = (const float*)d_in[19];
    const float* b_hh = (const float*)d_in[20];
    const float* Wi1 = (const float*)d_in[21];
    const float* bi1 = (const float*)d_in[22];
    const float* Wi2 = (const float*)d_in[23];
    const float* bi2 = (const float*)d_in[24];
    const float* lni_g = (const float*)d_in[25];
    const float* lni_b = (const float*)d_in[26];

    float* out = (float*)d_out;
    char* W = (char*)d_ws;

    // ---- workspace layout (~319 MB) ----
    bf16_t* We1sT = (bf16_t*)(W + 0);           // 5x[1024,1024] bf16 (state half)
    bf16_t* We2T  = (bf16_t*)(W + 10485760L);
    bf16_t* WihT  = (bf16_t*)(W + 20971520L);   // [3072,1024]
    bf16_t* WhhT  = (bf16_t*)(W + 27262976L);
    bf16_t* Wi1T  = (bf16_t*)(W + 33554432L);   // [2048,4096]
    bf16_t* Wi2T  = (bf16_t*)(W + 50331648L);   // [4096,2048]
    float* ctxbias = (float*)(W + 67108864L);   // 5*8*1024
    float* modew   = (float*)(W + 67272704L);
    float* depthw  = (float*)(W + 67272768L);
    float* h1ws    = (float*)(W + 67276800L);   // 8x1024
    float* hdws    = (float*)(W + 67309568L);   // 8x512
    const long SB = 67325952L;
    bf16_t* stateS = (bf16_t*)(W + SB);                    // 6 x [8192,1024] bf16 slabs
    bf16_t* Zb     = (bf16_t*)(W + SB + 100663296L);       // [8192,1024] bf16 (pre-LN)
    bf16_t* memb   = (bf16_t*)(W + SB + 117440512L);       // [8192,1024] bf16
    bf16_t* nsB    = (bf16_t*)(W + SB + 134217728L);       // [8192,1024] bf16
    bf16_t* gi     = (bf16_t*)(W + SB + 150994944L);       // [8192,3072] bf16
    bf16_t* gh     = (bf16_t*)(W + SB + 201326592L);       // [8192,3072] bf16
    // lifetime aliases (implicit phase; gi/gh dead there):
    bf16_t* Y1     = gi;                                   // [8192,1024] bf16
    bf16_t* superb = gi;                                   // [8192,4096] bf16
    bf16_t* Yi     = (bf16_t*)(W + SB + 201326592L + 16777216L); // [8192,2048]
    bf16_t* Ypre   = gi;                                   // [8192,4096] bf16

    (void)in_sizes; (void)n_in; (void)out_size; (void)ws_size;

    dim3 tb(32, 8);

    // selectors + ctx-bias (parallelized GEMV: W read once total)
    colgemv8_k<<<dim3(64, 1), 256, 0, stream>>>(ctx, Wm1, 0, 1024, bm1, 0, h1ws, 0, 1);
    colgemv8_k<<<dim3(32, 1), 256, 0, stream>>>(ctx, Wd1, 0, 512, bd1, 0, hdws, 0, 1);
    colgemv8_k<<<dim3(64, 5), 256, 0, stream>>>(ctx, We1 + 1048576L, 2097152L, 1024,
                                                be1, 1024, ctxbias, 8192, 0);
    selB_k<<<8, 256, 0, stream>>>(h1ws, hdws, Wm2, bm2, Wd2, bd2,
                                  out + OUT_MODE, out + OUT_DEPTH, modew, depthw);

    // weight transpose+convert to bf16 [N,K]
    transpose_k<<<dim3(32, 32, 5), tb, 0, stream>>>(We1, We1sT, 1024, 1024, 2097152L, 1048576L);
    transpose_k<<<dim3(32, 32, 5), tb, 0, stream>>>(We2, We2T, 1024, 1024, 1048576L, 1048576L);
    transpose_k<<<dim3(96, 32, 1), tb, 0, stream>>>(W_ih, WihT, 1024, 3072, 0L, 0L);
    transpose_k<<<dim3(96, 32, 1), tb, 0, stream>>>(W_hh, WhhT, 1024, 3072, 0L, 0L);
    transpose_k<<<dim3(64, 128, 1), tb, 0, stream>>>(Wi1, Wi1T, 4096, 2048, 0L, 0L);
    transpose_k<<<dim3(128, 64, 1), tb, 0, stream>>>(Wi2, Wi2T, 2048, 4096, 0L, 0L);

    cvt_k<<<8192, 256, 0, stream>>>((const float4*)det, (ushort4*)stateS, 2097152);

    for (int t = 0; t < 5; ++t) {
        const bf16_t* stIn = stateS + (long)t * SLAB;
        bf16_t* stOut = stateS + (long)(t + 1) * SLAB;
        // Y1 = gelu(state @ We1_state + ctxbias[t])  [8192,1024] bf16
        gemm8p<4, 2, 2><<<dim3(8, 64, 1), 512, 0, stream>>>(
            stIn, We1sT + (long)t * 1048576, ctxbias + (long)t * 8192, Y1,
            stIn, We1sT + (long)t * 1048576, ctxbias + (long)t * 8192, Y1, 1024, 1024);
        // Zb = Y1 @ We2 + be2[t]  [8192,1024] bf16
        gemm8p<4, 2, 3><<<dim3(8, 64, 1), 512, 0, stream>>>(
            Y1, We2T + (long)t * 1048576, be2 + t * 1024, Zb,
            Y1, We2T + (long)t * 1048576, be2 + t * 1024, Zb, 1024, 1024);
        // next_state = LN(Zb) -> nsB (bf16)
        ln1024_k<<<8192, 256, 0, stream>>>(Zb, ln_g + t * 1024, ln_b + t * 1024, nsB);
        // gi = ns @ W_ih + b_ih ; gh = mem @ W_hh + b_hh (dual launch at t>0)
        if (t > 0)
            gemm8p<4, 2, 3><<<dim3(24, 64, 2), 512, 0, stream>>>(
                nsB, WihT, b_ih, gi,
                memb, WhhT, b_hh, gh, 3072, 1024);
        else
            gemm8p<4, 2, 3><<<dim3(24, 64, 1), 512, 0, stream>>>(
                nsB, WihT, b_ih, gi,
                nsB, WihT, b_ih, gi, 3072, 1024);
        if (t == 0)
            gru_k<true><<<8192, 256, 0, stream>>>(gi, gh, b_hh, nsB, memb, stOut);
        else
            gru_k<false><<<8192, 256, 0, stream>>>(gi, gh, b_hh, nsB, memb, stOut);
    }

    // implicit path (gi/gh region reused as superb/Yi/Ypre)
    cvt_k<<<32768, 256, 0, stream>>>((const float4*)super_, (ushort4*)superb, 8388608);
    gemm8p<4, 2, 1><<<dim3(16, 64, 1), 512, 0, stream>>>(
        superb, Wi1T, bi1, Yi, superb, Wi1T, bi1, Yi, 2048, 4096);
    gemm8p<4, 2, 3><<<dim3(32, 64, 1), 512, 0, stream>>>(
        Yi, Wi2T, bi2, Ypre, Yi, Wi2T, bi2, Ypre, 4096, 2048);
    ln4096_final_k<<<8192, 1024, 0, stream>>>(Ypre, lni_g, lni_b, stateS + SLAB, depthw,
                                              out + OUT_IMPL, out + OUT_EXPL,
                                              out + OUT_RESULT, modew);
}

// Round 10
// 1426.393 us; speedup vs baseline: 1.0308x; 1.0308x over previous
//
#include <hip/hip_runtime.h>
#include <hip/hip_bf16.h>
#include <math.h>

// ---------------------------------------------------------------------------
// InferenceEngine: B=8 S=1024 H=1024 M=4 STEPS=5, all fp32 I/O.
// Round 10: REVERT to round-8 (best measured, 1432 us). r9's 2-block/CU
// experiment flipped the GEMM to HBM-bound (FETCH 102->556 MB) — refuted.
// GEMM bracketed on schedule AND occupancy axes; r8 is the operating optimum.
// ---------------------------------------------------------------------------

typedef unsigned short bf16_t;
typedef __attribute__((ext_vector_type(8))) short s8v;   // 8 x bf16 (4 VGPR)
typedef __attribute__((ext_vector_type(4))) float f4v;   // MFMA acc

typedef const __attribute__((address_space(1))) void* gas_ptr;
typedef __attribute__((address_space(3))) void* las_ptr;

#define DEVFN static __device__ __forceinline__

DEVFN bf16_t f2b(float f) {
    union { float f; unsigned u; } v; v.f = f;
    unsigned r = v.u + 0x7FFFu + ((v.u >> 16) & 1u);   // RNE
    return (bf16_t)(r >> 16);
}
DEVFN float b2f(bf16_t b) {
    union { unsigned u; float f; } v; v.u = ((unsigned)b) << 16; return v.f;
}
DEVFN float geluf(float x) { return 0.5f * x * (1.0f + erff(x * 0.70710678118654752f)); }
DEVFN float sigmf(float x) { return 1.0f / (1.0f + expf(-x)); }

// ------------------------- output layout (floats) ---------------------------
static const long OUT_RESULT = 0;           // 8*1024*1024
static const long OUT_MODE   = 8388608;     // 8*2
static const long OUT_DEPTH  = 8388624;     // 8*5
static const long OUT_EXPL   = 8388664;     // 8*1024*1024
static const long OUT_IMPL   = 16777272;    // 8*1024*4096

static const long SLAB = 8388608;           // elements per state slab

// ---------------------------------------------------------------------------
// 8-phase GEMM (round-4 schedule, measured best). C = A * Bt^T.
// 512 thr = 8 waves (2M x 4N). BM = MF*32, BN = NF*64, BK = 64.
// blockIdx.z selects pointer set {A,Bt,bias,out} (dual-GEMM launches).
//   ph1: READ A-hi + B-hi (buf c)   ; MFMA q(0,0)
//   ph2: MFMA q(1,0)                ; lgkmcnt(0) ; bar
//   ph3: stage tile t+2 -> buf c    ; MFMA q(1,1) ; vmcnt(LPT) ; bar
//   ph4: READ B-lo (c^1) ; MFMA q(0,1) ; READ A-lo (c^1)
// EPI: 1 = gelu(+bias1d) ; 2 = gelu(+bias2d[batch]) ; 3 = +bias1d  (bf16 out)
// ---------------------------------------------------------------------------
#define READ_A(h, c_) { _Pragma("unroll") \
    for (int mf = 0; mf < MF / 2; ++mf) { _Pragma("unroll") \
      for (int ks = 0; ks < 2; ++ks) { \
        aA[h][mf][ks] = *(const s8v*)(lds + (c_) * BUFB + \
            (arow_base + ((h) * (MF / 2) + mf) * 16) * 128 + \
            ((((ks << 2) + lhi) ^ l7) << 4)); } } }

#define READ_B(h, c_) { _Pragma("unroll") \
    for (int nf = 0; nf < NF / 2; ++nf) { _Pragma("unroll") \
      for (int ks = 0; ks < 2; ++ks) { \
        bB[h][nf][ks] = *(const s8v*)(lds + (c_) * BUFB + ABYTES + \
            (brow_base + ((h) * (NF / 2) + nf) * 16) * 128 + \
            ((((ks << 2) + lhi) ^ l7) << 4)); } } }

#define MFMAQ(mh, nh) { __builtin_amdgcn_s_setprio(1); _Pragma("unroll") \
    for (int mf = 0; mf < MF / 2; ++mf) { _Pragma("unroll") \
      for (int nf = 0; nf < NF / 2; ++nf) { _Pragma("unroll") \
        for (int ks = 0; ks < 2; ++ks) { \
          acc[(mh) * (MF / 2) + mf][(nh) * (NF / 2) + nf] = \
            __builtin_amdgcn_mfma_f32_16x16x32_bf16(aA[mh][mf][ks], bB[nh][nf][ks], \
                acc[(mh) * (MF / 2) + mf][(nh) * (NF / 2) + nf], 0, 0, 0); } } } \
    __builtin_amdgcn_s_setprio(0); }

#define WAIT_VM_LPT() { if (LPT == 8) asm volatile("s_waitcnt vmcnt(8)" ::: "memory"); \
                        else          asm volatile("s_waitcnt vmcnt(6)" ::: "memory"); }

template <int MF, int NF, int EPI>
__global__ __launch_bounds__(512, 2) void gemm8p(
    const bf16_t* __restrict__ A0, const bf16_t* __restrict__ Bt0,
    const float* __restrict__ bias0, bf16_t* __restrict__ out0,
    const bf16_t* __restrict__ A1, const bf16_t* __restrict__ Bt1,
    const float* __restrict__ bias1, bf16_t* __restrict__ out1,
    int N, int K)
{
    constexpr int BM = MF * 32;
    constexpr int BN = NF * 64;
    constexpr int LA = BM / 64;          // A global_load_lds per thread per tile
    constexpr int LB = BN / 64;
    constexpr int LPT = LA + LB;
    constexpr int ABYTES = BM * 128;     // BM rows x 64 k x 2B
    constexpr int BUFB = (BM + BN) * 128;

    __shared__ __align__(16) char lds[2 * BUFB];

    // pointer-set select (wave-uniform SGPR select)
    const bf16_t* A    = blockIdx.z ? A1 : A0;
    const bf16_t* Bt   = blockIdx.z ? Bt1 : Bt0;
    const float*  bias = blockIdx.z ? bias1 : bias0;
    bf16_t*       outB = blockIdx.z ? out1 : out0;

    const int tid  = threadIdx.x;
    const int lane = tid & 63;
    const int wave = tid >> 6;
    const int wm = wave >> 2, wn = wave & 3;
    const int l15 = lane & 15, lhi = lane >> 4, l7 = lane & 7;

    // T1: bijective XCD-chunked swizzle (per z-slice)
    const int gx = gridDim.x;
    const int nwg = gx * gridDim.y;
    const int orig = blockIdx.y * gx + blockIdx.x;
    const int qq = nwg >> 3, rr8 = nwg & 7;
    const int xcd = orig & 7, lid = orig >> 3;
    const int nid = (xcd < rr8 ? xcd * (qq + 1) : rr8 * (qq + 1) + (xcd - rr8) * qq) + lid;
    const int m0 = (nid / gx) * BM;
    const int n0 = (nid % gx) * BN;

    const int NT = K >> 6;

    const int arow_base = wm * (BM / 2) + l15;
    const int brow_base = wn * (NF * 16) + l15;

    f4v acc[MF][NF];
#pragma unroll
    for (int i = 0; i < MF; ++i)
#pragma unroll
        for (int j = 0; j < NF; ++j)
#pragma unroll
            for (int q2 = 0; q2 < 4; ++q2) acc[i][j][q2] = 0.0f;

    s8v aA[2][MF / 2][2];
    s8v bB[2][NF / 2][2];

    auto stage = [&](int ts, int tb) {
        const int kt = ts << 6;
#pragma unroll
        for (int i = 0; i < LA; ++i) {
            const int li = i * 512 + tid;
            const int r = li >> 3, s = li & 7;
            const bf16_t* src = A + (long)(m0 + r) * K + kt + ((s ^ (r & 7)) << 3);
            __builtin_amdgcn_global_load_lds((gas_ptr)src, (las_ptr)(lds + tb * BUFB + li * 16), 16, 0, 0);
        }
#pragma unroll
        for (int i = 0; i < LB; ++i) {
            const int li = i * 512 + tid;
            const int r = li >> 3, s = li & 7;
            const bf16_t* src = Bt + (long)(n0 + r) * K + kt + ((s ^ (r & 7)) << 3);
            __builtin_amdgcn_global_load_lds((gas_ptr)src, (las_ptr)(lds + tb * BUFB + ABYTES + li * 16), 16, 0, 0);
        }
    };

    // prologue: tiles 0,1 in flight; wait tile 0; first q1 operands
    stage(0, 0);
    stage(1, 1);
    WAIT_VM_LPT();
    __builtin_amdgcn_sched_barrier(0);
    __builtin_amdgcn_s_barrier();
    READ_A(0, 0);
    READ_B(0, 0);

    for (int t = 0; t < NT; ++t) {
        const int c = t & 1;
        // ph1: hi-half reads issued a full quadrant before their first use
        READ_A(1, c);
        READ_B(1, c);
        MFMAQ(0, 0);
        // ph2
        MFMAQ(1, 0);
        asm volatile("s_waitcnt lgkmcnt(0)" ::: "memory");
        __builtin_amdgcn_sched_barrier(0);
        __builtin_amdgcn_s_barrier();                 // B1: all buf[c] reads retired
        // ph3
        int ts = t + 2; if (ts >= NT) ts -= NT;       // wrap: harmless warm re-stage
        stage(ts, c);
        MFMAQ(1, 1);
        WAIT_VM_LPT();                                // tile t+1 fully in buf[c^1]
        __builtin_amdgcn_sched_barrier(0);
        __builtin_amdgcn_s_barrier();                 // B2
        // ph4: B-lo read first (bB[0] dead since ph2), then MFMA frees aA[0]
        READ_B(0, c ^ 1);
        MFMAQ(0, 1);
        READ_A(0, c ^ 1);
    }

    // epilogue. C/D layout: col = lane&15, row = (lane>>4)*4 + q
    const int crr = lhi << 2;
#pragma unroll
    for (int mi = 0; mi < MF; ++mi) {
#pragma unroll
        for (int ni = 0; ni < NF; ++ni) {
            const int col = n0 + wn * (NF * 16) + ni * 16 + (lane & 15);
#pragma unroll
            for (int q2 = 0; q2 < 4; ++q2) {
                const int row = m0 + wm * (BM / 2) + mi * 16 + crr + q2;
                const float v = acc[mi][ni][q2];
                if (EPI == 1) {
                    outB[(long)row * N + col] = f2b(geluf(v + bias[col]));
                } else if (EPI == 2) {
                    outB[(long)row * N + col] = f2b(geluf(v + bias[(long)(row >> 10) * N + col]));
                } else {
                    outB[(long)row * N + col] = f2b(v + bias[col]);
                }
            }
        }
    }
}

// --------------------- transpose f32[K,N] -> bf16[N,K] ----------------------
__global__ __launch_bounds__(256) void transpose_k(
    const float* __restrict__ src, bf16_t* __restrict__ dst,
    int K, int N, long sbs, long dbs)
{
    __shared__ float tile[32][33];
    const float* s = src + (long)blockIdx.z * sbs;
    bf16_t* d = dst + (long)blockIdx.z * dbs;
    const int n0 = blockIdx.x * 32, k0 = blockIdx.y * 32;
    const int tx = threadIdx.x, ty = threadIdx.y;   // 32 x 8
#pragma unroll
    for (int i = 0; i < 4; ++i)
        tile[ty + i * 8][tx] = s[(long)(k0 + ty + i * 8) * N + n0 + tx];
    __syncthreads();
#pragma unroll
    for (int i = 0; i < 4; ++i)
        d[(long)(n0 + ty + i * 8) * K + k0 + tx] = f2b(tile[tx][ty + i * 8]);
}

// --------------------------- f32 -> bf16 convert ----------------------------
__global__ __launch_bounds__(256) void cvt_k(const float4* __restrict__ src,
                                             ushort4* __restrict__ dst, int n4)
{
    const int i = blockIdx.x * 256 + threadIdx.x;
    if (i < n4) {
        float4 v = src[i];
        ushort4 o; o.x = f2b(v.x); o.y = f2b(v.y); o.z = f2b(v.z); o.w = f2b(v.w);
        dst[i] = o;
    }
}

// ---------------------------------------------------------------------------
// colgemv8: out[t*ots + b*Wld + j] = act(bias[t*bts+j] + sum_k ctx[b][k]*W[t*wts+k*Wld+j])
// ---------------------------------------------------------------------------
__global__ __launch_bounds__(256) void colgemv8_k(
    const float* __restrict__ ctx, const float* __restrict__ Wbase, long wts,
    int Wld, const float* __restrict__ bias, long bts,
    float* __restrict__ out, long ots, int do_gelu)
{
    __shared__ float cs[8][1024];
    __shared__ float rr[16][16][8];
    const int j0 = blockIdx.x * 16;
    const int t = blockIdx.y;
    const int tid = threadIdx.x;
    for (int i = tid; i < 2048; i += 256)
        ((float4*)cs)[i] = ((const float4*)ctx)[i];
    __syncthreads();
    const int kp = tid >> 4, jj = tid & 15;
    const float* Wp = Wbase + (long)t * wts;
    float p[8] = {0, 0, 0, 0, 0, 0, 0, 0};
    for (int i = 0; i < 64; ++i) {
        const int k = kp * 64 + i;
        const float w = Wp[(long)k * Wld + j0 + jj];
#pragma unroll
        for (int b = 0; b < 8; ++b) p[b] = fmaf(cs[b][k], w, p[b]);
    }
#pragma unroll
    for (int b = 0; b < 8; ++b) rr[kp][jj][b] = p[b];
    __syncthreads();
    if (tid < 128) {
        const int jj2 = tid >> 3, b = tid & 7;
        float s = 0.f;
#pragma unroll
        for (int k2 = 0; k2 < 16; ++k2) s += rr[k2][jj2][b];
        s += bias[(long)t * bts + j0 + jj2];
        if (do_gelu) s = geluf(s);
        out[(long)t * ots + (long)b * Wld + j0 + jj2] = s;
    }
}

// -------------- selectors tail: [8,2] and [8,5] softmaxes -------------------
__global__ __launch_bounds__(256) void selB_k(
    const float* __restrict__ h1, const float* __restrict__ hd,
    const float* __restrict__ Wm2, const float* __restrict__ bm2,
    const float* __restrict__ Wd2, const float* __restrict__ bd2,
    float* __restrict__ outM, float* __restrict__ outD,
    float* __restrict__ wsM, float* __restrict__ wsD)
{
    const int b = blockIdx.x, tid = threadIdx.x;
    __shared__ float red[256];
    float lm[2], ld[5];
    for (int o = 0; o < 2; ++o) {
        float p = 0.f;
        for (int k = tid; k < 1024; k += 256) p += h1[b * 1024 + k] * Wm2[k * 2 + o];
        red[tid] = p; __syncthreads();
        for (int s = 128; s > 0; s >>= 1) { if (tid < s) red[tid] += red[tid + s]; __syncthreads(); }
        lm[o] = red[0] + bm2[o]; __syncthreads();
    }
    for (int o = 0; o < 5; ++o) {
        float p = 0.f;
        for (int k = tid; k < 512; k += 256) p += hd[b * 512 + k] * Wd2[k * 5 + o];
        red[tid] = p; __syncthreads();
        for (int s = 128; s > 0; s >>= 1) { if (tid < s) red[tid] += red[tid + s]; __syncthreads(); }
        ld[o] = red[0] + bd2[o]; __syncthreads();
    }
    if (tid == 0) {
        float mx = fmaxf(lm[0], lm[1]);
        float e0 = expf(lm[0] - mx), e1 = expf(lm[1] - mx);
        float inv = 1.f / (e0 + e1);
        outM[b * 2] = e0 * inv; outM[b * 2 + 1] = e1 * inv;
        wsM[b * 2] = e0 * inv;  wsM[b * 2 + 1] = e1 * inv;
        float md = ld[0];
        for (int o = 1; o < 5; ++o) md = fmaxf(md, ld[o]);
        float es[5]; float sum = 0.f;
        for (int o = 0; o < 5; ++o) { es[o] = expf(ld[o] - md); sum += es[o]; }
        for (int o = 0; o < 5; ++o) { outD[b * 5 + o] = es[o] / sum; wsD[b * 5 + o] = es[o] / sum; }
    }
}

// --------------------- LayerNorm over 1024 (bf16 in/out) --------------------
__global__ __launch_bounds__(256) void ln1024_k(
    const bf16_t* __restrict__ X, const float* __restrict__ g,
    const float* __restrict__ b, bf16_t* __restrict__ Yb)
{
    const int row = blockIdx.x, tid = threadIdx.x;
    const ushort4 xv = ((const ushort4*)(X + (long)row * 1024))[tid];
    const float x0 = b2f(xv.x), x1 = b2f(xv.y), x2 = b2f(xv.z), x3 = b2f(xv.w);
    float s = x0 + x1 + x2 + x3;
    float ss = x0 * x0 + x1 * x1 + x2 * x2 + x3 * x3;
#pragma unroll
    for (int o = 32; o > 0; o >>= 1) { s += __shfl_down(s, o); ss += __shfl_down(ss, o); }
    __shared__ float rs[4], rss[4];
    const int wv = tid >> 6, ln = tid & 63;
    if (ln == 0) { rs[wv] = s; rss[wv] = ss; }
    __syncthreads();
    const float S = rs[0] + rs[1] + rs[2] + rs[3];
    const float SS = rss[0] + rss[1] + rss[2] + rss[3];
    const float mean = S * (1.0f / 1024.0f);
    const float var = SS * (1.0f / 1024.0f) - mean * mean;
    const float rstd = rsqrtf(var + 1e-5f);
    const float4 gv = ((const float4*)g)[tid];
    const float4 bv = ((const float4*)b)[tid];
    ushort4 ob;
    ob.x = f2b((x0 - mean) * rstd * gv.x + bv.x);
    ob.y = f2b((x1 - mean) * rstd * gv.y + bv.y);
    ob.z = f2b((x2 - mean) * rstd * gv.z + bv.z);
    ob.w = f2b((x3 - mean) * rstd * gv.w + bv.w);
    ((ushort4*)(Yb + (long)row * 1024))[tid] = ob;
}

// ------------------- GRU gate; writes mem + gated state slab ----------------
template <bool FIRST>
__global__ __launch_bounds__(256) void gru_k(
    const bf16_t* __restrict__ gi, const bf16_t* __restrict__ gh,
    const float* __restrict__ bhh, const bf16_t* __restrict__ nsB,
    bf16_t* __restrict__ memB, bf16_t* __restrict__ stateOut)
{
    const long i4 = (long)blockIdx.x * 256 + threadIdx.x;
    const long row = i4 >> 8;
    const int h4 = (int)(i4 & 255) << 2;
    const bf16_t* gir = gi + row * 3072 + h4;
    const ushort4 vir = *(const ushort4*)(gir);
    const ushort4 viz = *(const ushort4*)(gir + 1024);
    const ushort4 vin = *(const ushort4*)(gir + 2048);
    float hr[4], hz[4], hn[4];
    if (FIRST) {
        const float4 a = *(const float4*)(bhh + h4);
        const float4 c = *(const float4*)(bhh + 1024 + h4);
        const float4 d = *(const float4*)(bhh + 2048 + h4);
        hr[0] = a.x; hr[1] = a.y; hr[2] = a.z; hr[3] = a.w;
        hz[0] = c.x; hz[1] = c.y; hz[2] = c.z; hz[3] = c.w;
        hn[0] = d.x; hn[1] = d.y; hn[2] = d.z; hn[3] = d.w;
    } else {
        const bf16_t* ghr = gh + row * 3072 + h4;
        const ushort4 g1 = *(const ushort4*)(ghr);
        const ushort4 g2 = *(const ushort4*)(ghr + 1024);
        const ushort4 g3 = *(const ushort4*)(ghr + 2048);
        hr[0] = b2f(g1.x); hr[1] = b2f(g1.y); hr[2] = b2f(g1.z); hr[3] = b2f(g1.w);
        hz[0] = b2f(g2.x); hz[1] = b2f(g2.y); hz[2] = b2f(g2.z); hz[3] = b2f(g2.w);
        hn[0] = b2f(g3.x); hn[1] = b2f(g3.y); hn[2] = b2f(g3.z); hn[3] = b2f(g3.w);
    }
    const ushort4 nsv = *(const ushort4*)(nsB + row * 1024 + h4);
    float mo[4] = {0.f, 0.f, 0.f, 0.f};
    if (!FIRST) {
        const ushort4 mv = *(const ushort4*)(memB + row * 1024 + h4);
        mo[0] = b2f(mv.x); mo[1] = b2f(mv.y); mo[2] = b2f(mv.z); mo[3] = b2f(mv.w);
    }
    const float ir[4] = {b2f(vir.x), b2f(vir.y), b2f(vir.z), b2f(vir.w)};
    const float iz[4] = {b2f(viz.x), b2f(viz.y), b2f(viz.z), b2f(viz.w)};
    const float in_[4] = {b2f(vin.x), b2f(vin.y), b2f(vin.z), b2f(vin.w)};
    const float ns[4] = {b2f(nsv.x), b2f(nsv.y), b2f(nsv.z), b2f(nsv.w)};
    ushort4 mnb, stb;
    float mn[4], gt[4];
#pragma unroll
    for (int i = 0; i < 4; ++i) {
        const float rg = sigmf(ir[i] + hr[i]);
        const float zg = sigmf(iz[i] + hz[i]);
        const float ng = tanhf(in_[i] + rg * hn[i]);
        mn[i] = (1.0f - zg) * ng + zg * mo[i];
        gt[i] = ns[i] + 0.1f * mn[i];
    }
    mnb.x = f2b(mn[0]); mnb.y = f2b(mn[1]); mnb.z = f2b(mn[2]); mnb.w = f2b(mn[3]);
    stb.x = f2b(gt[0]); stb.y = f2b(gt[1]); stb.z = f2b(gt[2]); stb.w = f2b(gt[3]);
    *(ushort4*)(memB + row * 1024 + h4) = mnb;
    *(ushort4*)(stateOut + row * 1024 + h4) = stb;
}

// --- implicit LN (4096) + implicit_det + expl-from-slabs + final combine ----
__global__ __launch_bounds__(1024) void ln4096_final_k(
    const bf16_t* __restrict__ Ypre, const float* __restrict__ g,
    const float* __restrict__ b, const bf16_t* __restrict__ stS,
    const float* __restrict__ depthw, float* __restrict__ implOut,
    float* __restrict__ explOut, float* __restrict__ result,
    const float* __restrict__ modew)
{
    const int row = blockIdx.x, tid = threadIdx.x;
    const ushort4 xv = ((const ushort4*)(Ypre + (long)row * 4096))[tid];
    const float x0 = b2f(xv.x), x1 = b2f(xv.y), x2 = b2f(xv.z), x3 = b2f(xv.w);
    float s = x0 + x1 + x2 + x3;
    float ss = x0 * x0 + x1 * x1 + x2 * x2 + x3 * x3;
#pragma unroll
    for (int o = 32; o > 0; o >>= 1) { s += __shfl_down(s, o); ss += __shfl_down(ss, o); }
    __shared__ float rs[16], rss[16];
    __shared__ float ylds[4096];
    const int wv = tid >> 6, ln = tid & 63;
    if (ln == 0) { rs[wv] = s; rss[wv] = ss; }
    __syncthreads();
    if (tid < 64) {
        float a = (ln < 16) ? rs[ln] : 0.f;
        float c2 = (ln < 16) ? rss[ln] : 0.f;
#pragma unroll
        for (int o = 8; o > 0; o >>= 1) { a += __shfl_down(a, o); c2 += __shfl_down(c2, o); }
        if (ln == 0) { rs[0] = a; rss[0] = c2; }
    }
    __syncthreads();
    const float mean = rs[0] * (1.f / 4096.f);
    const float var = rss[0] * (1.f / 4096.f) - mean * mean;
    const float rstd = rsqrtf(var + 1e-5f);
    const float4 gv = ((const float4*)g)[tid];
    const float4 bv = ((const float4*)b)[tid];
    float4 y;
    y.x = (x0 - mean) * rstd * gv.x + bv.x;
    y.y = (x1 - mean) * rstd * gv.y + bv.y;
    y.z = (x2 - mean) * rstd * gv.z + bv.z;
    y.w = (x3 - mean) * rstd * gv.w + bv.w;
    ((float4*)(implOut + (long)row * 4096))[tid] = y;
    ((float4*)ylds)[tid] = y;
    __syncthreads();
    const int bidx = row >> 10;
    const long off = (long)row * 1024 + tid;
    float ex = 0.f;
#pragma unroll
    for (int tt = 0; tt < 5; ++tt)
        ex += depthw[bidx * 5 + tt] * b2f(stS[(long)tt * SLAB + off]);
    explOut[off] = ex;
    const float det4 = 0.25f * (ylds[tid] + ylds[tid + 1024] + ylds[tid + 2048] + ylds[tid + 3072]);
    result[off] = modew[bidx * 2] * det4 + modew[bidx * 2 + 1] * ex;
}

// ---------------------------------------------------------------------------
extern "C" void kernel_launch(void* const* d_in, const int* in_sizes, int n_in,
                              void* d_out, int out_size, void* d_ws, size_t ws_size,
                              hipStream_t stream)
{
    const float* det    = (const float*)d_in[0];
    const float* super_ = (const float*)d_in[1];
    const float* ctx    = (const float*)d_in[2];
    const float* Wm1 = (const float*)d_in[3];
    const float* bm1 = (const float*)d_in[4];
    const float* Wm2 = (const float*)d_in[5];
    const float* bm2 = (const float*)d_in[6];
    const float* Wd1 = (const float*)d_in[7];
    const float* bd1 = (const float*)d_in[8];
    const float* Wd2 = (const float*)d_in[9];
    const float* bd2 = (const float*)d_in[10];
    const float* We1 = (const float*)d_in[11];
    const float* be1 = (const float*)d_in[12];
    const float* We2 = (const float*)d_in[13];
    const float* be2 = (const float*)d_in[14];
    const float* ln_g = (const float*)d_in[15];
    const float* ln_b = (const float*)d_in[16];
    const float* W_ih = (const float*)d_in[17];
    const float* W_hh = (const float*)d_in[18];
    const float* b_ih = (const float*)d_in[19];
    const float* b_hh = (const float*)d_in[20];
    const float* Wi1 = (const float*)d_in[21];
    const float* bi1 = (const float*)d_in[22];
    const float* Wi2 = (const float*)d_in[23];
    const float* bi2 = (const float*)d_in[24];
    const float* lni_g = (const float*)d_in[25];
    const float* lni_b = (const float*)d_in[26];

    float* out = (float*)d_out;
    char* W = (char*)d_ws;

    // ---- workspace layout (~319 MB) ----
    bf16_t* We1sT = (bf16_t*)(W + 0);           // 5x[1024,1024] bf16 (state half)
    bf16_t* We2T  = (bf16_t*)(W + 10485760L);
    bf16_t* WihT  = (bf16_t*)(W + 20971520L);   // [3072,1024]
    bf16_t* WhhT  = (bf16_t*)(W + 27262976L);
    bf16_t* Wi1T  = (bf16_t*)(W + 33554432L);   // [2048,4096]
    bf16_t* Wi2T  = (bf16_t*)(W + 50331648L);   // [4096,2048]
    float* ctxbias = (float*)(W + 67108864L);   // 5*8*1024
    float* modew   = (float*)(W + 67272704L);
    float* depthw  = (float*)(W + 67272768L);
    float* h1ws    = (float*)(W + 67276800L);   // 8x1024
    float* hdws    = (float*)(W + 67309568L);   // 8x512
    const long SB = 67325952L;
    bf16_t* stateS = (bf16_t*)(W + SB);                    // 6 x [8192,1024] bf16 slabs
    bf16_t* Zb     = (bf16_t*)(W + SB + 100663296L);       // [8192,1024] bf16 (pre-LN)
    bf16_t* memb   = (bf16_t*)(W + SB + 117440512L);       // [8192,1024] bf16
    bf16_t* nsB    = (bf16_t*)(W + SB + 134217728L);       // [8192,1024] bf16
    bf16_t* gi     = (bf16_t*)(W + SB + 150994944L);       // [8192,3072] bf16
    bf16_t* gh     = (bf16_t*)(W + SB + 201326592L);       // [8192,3072] bf16
    // lifetime aliases (implicit phase; gi/gh dead there):
    bf16_t* Y1     = gi;                                   // [8192,1024] bf16
    bf16_t* superb = gi;                                   // [8192,4096] bf16
    bf16_t* Yi     = (bf16_t*)(W + SB + 201326592L + 16777216L); // [8192,2048]
    bf16_t* Ypre   = gi;                                   // [8192,4096] bf16

    (void)in_sizes; (void)n_in; (void)out_size; (void)ws_size;

    dim3 tb(32, 8);

    // selectors + ctx-bias (parallelized GEMV: W read once total)
    colgemv8_k<<<dim3(64, 1), 256, 0, stream>>>(ctx, Wm1, 0, 1024, bm1, 0, h1ws, 0, 1);
    colgemv8_k<<<dim3(32, 1), 256, 0, stream>>>(ctx, Wd1, 0, 512, bd1, 0, hdws, 0, 1);
    colgemv8_k<<<dim3(64, 5), 256, 0, stream>>>(ctx, We1 + 1048576L, 2097152L, 1024,
                                                be1, 1024, ctxbias, 8192, 0);
    selB_k<<<8, 256, 0, stream>>>(h1ws, hdws, Wm2, bm2, Wd2, bd2,
                                  out + OUT_MODE, out + OUT_DEPTH, modew, depthw);

    // weight transpose+convert to bf16 [N,K]
    transpose_k<<<dim3(32, 32, 5), tb, 0, stream>>>(We1, We1sT, 1024, 1024, 2097152L, 1048576L);
    transpose_k<<<dim3(32, 32, 5), tb, 0, stream>>>(We2, We2T, 1024, 1024, 1048576L, 1048576L);
    transpose_k<<<dim3(96, 32, 1), tb, 0, stream>>>(W_ih, WihT, 1024, 3072, 0L, 0L);
    transpose_k<<<dim3(96, 32, 1), tb, 0, stream>>>(W_hh, WhhT, 1024, 3072, 0L, 0L);
    transpose_k<<<dim3(64, 128, 1), tb, 0, stream>>>(Wi1, Wi1T, 4096, 2048, 0L, 0L);
    transpose_k<<<dim3(128, 64, 1), tb, 0, stream>>>(Wi2, Wi2T, 2048, 4096, 0L, 0L);

    cvt_k<<<8192, 256, 0, stream>>>((const float4*)det, (ushort4*)stateS, 2097152);

    for (int t = 0; t < 5; ++t) {
        const bf16_t* stIn = stateS + (long)t * SLAB;
        bf16_t* stOut = stateS + (long)(t + 1) * SLAB;
        // Y1 = gelu(state @ We1_state + ctxbias[t])  [8192,1024] bf16
        gemm8p<4, 4, 2><<<dim3(4, 64, 1), 512, 0, stream>>>(
            stIn, We1sT + (long)t * 1048576, ctxbias + (long)t * 8192, Y1,
            stIn, We1sT + (long)t * 1048576, ctxbias + (long)t * 8192, Y1, 1024, 1024);
        // Zb = Y1 @ We2 + be2[t]  [8192,1024] bf16
        gemm8p<4, 4, 3><<<dim3(4, 64, 1), 512, 0, stream>>>(
            Y1, We2T + (long)t * 1048576, be2 + t * 1024, Zb,
            Y1, We2T + (long)t * 1048576, be2 + t * 1024, Zb, 1024, 1024);
        // next_state = LN(Zb) -> nsB (bf16)
        ln1024_k<<<8192, 256, 0, stream>>>(Zb, ln_g + t * 1024, ln_b + t * 1024, nsB);
        // gi = ns @ W_ih + b_ih ; gh = mem @ W_hh + b_hh (dual launch at t>0)
        if (t > 0)
            gemm8p<4, 4, 3><<<dim3(12, 64, 2), 512, 0, stream>>>(
                nsB, WihT, b_ih, gi,
                memb, WhhT, b_hh, gh, 3072, 1024);
        else
            gemm8p<4, 4, 3><<<dim3(12, 64, 1), 512, 0, stream>>>(
                nsB, WihT, b_ih, gi,
                nsB, WihT, b_ih, gi, 3072, 1024);
        if (t == 0)
            gru_k<true><<<8192, 256, 0, stream>>>(gi, gh, b_hh, nsB, memb, stOut);
        else
            gru_k<false><<<8192, 256, 0, stream>>>(gi, gh, b_hh, nsB, memb, stOut);
    }

    // implicit path (gi/gh region reused as superb/Yi/Ypre)
    cvt_k<<<32768, 256, 0, stream>>>((const float4*)super_, (ushort4*)superb, 8388608);
    gemm8p<8, 4, 1><<<dim3(8, 32, 1), 512, 0, stream>>>(
        superb, Wi1T, bi1, Yi, superb, Wi1T, bi1, Yi, 2048, 4096);
    gemm8p<8, 4, 3><<<dim3(16, 32, 1), 512, 0, stream>>>(
        Yi, Wi2T, bi2, Ypre, Yi, Wi2T, bi2, Ypre, 4096, 2048);
    ln4096_final_k<<<8192, 1024, 0, stream>>>(Ypre, lni_g, lni_b, stateS + SLAB, depthw,
                                              out + OUT_IMPL, out + OUT_EXPL,
                                              out + OUT_RESULT, modew);
}